// Round 1
// baseline (3636.573 us; speedup 1.0000x reference)
//
#include <hip/hip_runtime.h>
#include <math.h>

#define HWq 10000
#define Cq 256

// ---------------------------------------------------------------------------
// Kernel 1: 1x1 conv as fp32 GEMM  y[b,o,p] = sum_c W[o,c] * F[b,c,p]
// Tile: 64 o x 64 p per block (256 threads, 4x4 microtile), K chunks of 16.
// Also accumulates per-batch sum / sumsq of y into stats[0..7], stats[8..15].
// ---------------------------------------------------------------------------
__global__ __launch_bounds__(256) void conv_gemm(const float* __restrict__ feat,
                                                 const float* __restrict__ convw,
                                                 float* __restrict__ y,
                                                 float* __restrict__ stats) {
    __shared__ float As[16][64];   // [k][o]
    __shared__ float Bs[16][64];   // [k][p]
    __shared__ float redbuf[8];

    const int b  = blockIdx.z;
    const int o0 = blockIdx.y * 64;
    const int p0 = blockIdx.x * 64;
    const int t  = threadIdx.x;
    const int tx = t & 15;         // p group
    const int ty = t >> 4;         // o group

    const float* fb = feat + (size_t)b * Cq * HWq;

    float acc[4][4] = {};

    for (int k0 = 0; k0 < Cq; k0 += 16) {
        // load A chunk: conv_w rows o0..o0+63, cols k0..k0+15 (store transposed)
        #pragma unroll
        for (int pass = 0; pass < 4; ++pass) {
            int i = (t >> 4) + pass * 16;   // o 0..63
            int j = t & 15;                 // k 0..15
            As[j][i] = convw[(o0 + i) * Cq + k0 + j];
        }
        // load B chunk: features rows k0..k0+15 (stride HW), cols p0..p0+63
        #pragma unroll
        for (int pass = 0; pass < 4; ++pass) {
            int r = (t >> 6) + pass * 4;    // k 0..15
            int c = t & 63;                 // p 0..63
            int p = p0 + c;
            if (p > HWq - 1) p = HWq - 1;   // clamp (unused cols never stored)
            Bs[r][c] = fb[(size_t)(k0 + r) * HWq + p];
        }
        __syncthreads();
        #pragma unroll
        for (int kk = 0; kk < 16; ++kk) {
            const float4 av = *reinterpret_cast<const float4*>(&As[kk][ty * 4]);
            const float4 bv = *reinterpret_cast<const float4*>(&Bs[kk][tx * 4]);
            acc[0][0] += av.x * bv.x; acc[0][1] += av.x * bv.y;
            acc[0][2] += av.x * bv.z; acc[0][3] += av.x * bv.w;
            acc[1][0] += av.y * bv.x; acc[1][1] += av.y * bv.y;
            acc[1][2] += av.y * bv.z; acc[1][3] += av.y * bv.w;
            acc[2][0] += av.z * bv.x; acc[2][1] += av.z * bv.y;
            acc[2][2] += av.z * bv.z; acc[2][3] += av.z * bv.w;
            acc[3][0] += av.w * bv.x; acc[3][1] += av.w * bv.y;
            acc[3][2] += av.w * bv.z; acc[3][3] += av.w * bv.w;
        }
        __syncthreads();
    }

    // store + local stats
    float lsum = 0.f, lsq = 0.f;
    #pragma unroll
    for (int i = 0; i < 4; ++i) {
        int o = o0 + ty * 4 + i;
        float* yrow = y + (size_t)(b * Cq + o) * HWq;
        #pragma unroll
        for (int j = 0; j < 4; ++j) {
            int p = p0 + tx * 4 + j;
            if (p < HWq) {
                float v = acc[i][j];
                yrow[p] = v;
                lsum += v;
                lsq  += v * v;
            }
        }
    }
    // wave reduce then block reduce
    #pragma unroll
    for (int m = 1; m < 64; m <<= 1) {
        lsum += __shfl_xor(lsum, m);
        lsq  += __shfl_xor(lsq, m);
    }
    int wave = t >> 6, lane = t & 63;
    if (lane == 0) { redbuf[wave] = lsum; redbuf[4 + wave] = lsq; }
    __syncthreads();
    if (t == 0) {
        atomicAdd(&stats[b],     redbuf[0] + redbuf[1] + redbuf[2] + redbuf[3]);
        atomicAdd(&stats[8 + b], redbuf[4] + redbuf[5] + redbuf[6] + redbuf[7]);
    }
}

// ---------------------------------------------------------------------------
// Kernel 2: per-box region pooling, fused with GroupNorm-normalize + SiLU.
// One block per (b,n). 4 waves; each wave owns 64 channels sequentially;
// lanes span box width.
// ---------------------------------------------------------------------------
__global__ __launch_bounds__(256) void pool_kernel(const float* __restrict__ y,
                                                   const float* __restrict__ boxes,
                                                   const float* __restrict__ stats,
                                                   const float* __restrict__ gnw,
                                                   const float* __restrict__ gnb,
                                                   float* __restrict__ pooled) {
    const int bn = blockIdx.x;      // 0..511
    const int b  = bn >> 6;

    const float* bx = boxes + (size_t)bn * 4;
    float bv0 = bx[0], bv1 = bx[1], bv2 = bx[2], bv3 = bx[3];

    float x1f = fminf(bv0, bv2) * 100.f;
    float x2f = fmaxf(bv0, bv2) * 100.f;
    float y1f = fminf(bv1, bv3) * 100.f;
    float y2f = fmaxf(bv1, bv3) * 100.f;
    x1f = fminf(fmaxf(floorf(fminf(fmaxf(x1f, 0.f), 100.f)), 0.f), 100.f);
    x2f = fminf(fmaxf(ceilf (fminf(fmaxf(x2f, 0.f), 100.f)), 0.f), 100.f);
    y1f = fminf(fmaxf(floorf(fminf(fmaxf(y1f, 0.f), 100.f)), 0.f), 100.f);
    y2f = fminf(fmaxf(ceilf (fminf(fmaxf(y2f, 0.f), 100.f)), 0.f), 100.f);
    const int ix1 = (int)x1f, ix2 = (int)x2f;
    const int iy1 = (int)y1f, iy2 = (int)y2f;
    const float cnt = (float)((ix2 - ix1) * (iy2 - iy1));

    const float invM = 1.f / 2560000.f;   // 1/(C*H*W)
    const float mu   = stats[b] * invM;
    const float msq  = stats[8 + b] * invM;
    const float rs   = rsqrtf(msq - mu * mu + 1e-5f);

    const int wave = threadIdx.x >> 6;
    const int lane = threadIdx.x & 63;

    for (int ci = 0; ci < 64; ++ci) {
        const int c = wave * 64 + ci;
        const float scale = gnw[c] * rs;
        const float shift = gnb[c] - mu * scale;
        float acc = 0.f;
        if (cnt > 0.f) {
            const float* yc = y + (size_t)(b * Cq + c) * HWq;
            for (int h = iy1; h < iy2; ++h) {
                const float* yr = yc + h * 100;
                for (int w = ix1 + lane; w < ix2; w += 64) {
                    float v = yr[w] * scale + shift;
                    acc += v / (1.f + __expf(-v));   // SiLU
                }
            }
        }
        #pragma unroll
        for (int m = 1; m < 64; m <<= 1) acc += __shfl_xor(acc, m);
        if (lane == 0)
            pooled[(size_t)bn * Cq + c] = (cnt > 0.f) ? acc / cnt : 0.f;
    }
}

// ---------------------------------------------------------------------------
// Kernel 3: MLP (256->128 SiLU ->64) + L2 normalize. One block per (b,n).
// ---------------------------------------------------------------------------
__global__ __launch_bounds__(128) void mlp_kernel(const float* __restrict__ pooled,
                                                  const float* __restrict__ w1,
                                                  const float* __restrict__ b1,
                                                  const float* __restrict__ w2,
                                                  const float* __restrict__ b2,
                                                  float* __restrict__ emb,
                                                  float* __restrict__ raw) {
    __shared__ float ps[256];
    __shared__ float hs[128];
    const int bn = blockIdx.x;
    const int t  = threadIdx.x;

    ps[t]       = pooled[(size_t)bn * 256 + t];
    ps[t + 128] = pooled[(size_t)bn * 256 + t + 128];
    __syncthreads();

    float a = b1[t];
    #pragma unroll 8
    for (int c = 0; c < 256; ++c) a += ps[c] * w1[c * 128 + t];
    hs[t] = a / (1.f + __expf(-a));
    __syncthreads();

    if (t < 64) {
        float r = b2[t];
        #pragma unroll 8
        for (int h = 0; h < 128; ++h) r += hs[h] * w2[h * 64 + t];
        raw[(size_t)bn * 64 + t] = r;
        float s = r * r;
        #pragma unroll
        for (int m = 1; m < 64; m <<= 1) s += __shfl_xor(s, m);
        float nrm = fmaxf(sqrtf(s), 1e-6f);
        emb[(size_t)bn * 64 + t] = r / nrm;
    }
}

// ---------------------------------------------------------------------------
extern "C" void kernel_launch(void* const* d_in, const int* in_sizes, int n_in,
                              void* d_out, int out_size, void* d_ws, size_t ws_size,
                              hipStream_t stream) {
    const float* feat  = (const float*)d_in[0];
    const float* boxes = (const float*)d_in[1];
    const float* convw = (const float*)d_in[2];
    const float* gnw   = (const float*)d_in[3];
    const float* gnb   = (const float*)d_in[4];
    const float* w1    = (const float*)d_in[5];
    const float* b1    = (const float*)d_in[6];
    const float* w2    = (const float*)d_in[7];
    const float* b2    = (const float*)d_in[8];

    float* out    = (float*)d_out;
    float* emb    = out;             // [8,64,64]   = 32768
    float* raw    = out + 32768;     // [8,64,64]   = 32768
    float* pooled = out + 65536;     // [8,64,256]  = 131072

    float* y     = (float*)d_ws;                                   // 8*256*10000 f32
    float* stats = (float*)((char*)d_ws + (size_t)8 * 256 * 10000 * 4);

    hipMemsetAsync(stats, 0, 16 * sizeof(float), stream);

    dim3 g1((HWq + 63) / 64, 4, 8);
    conv_gemm<<<g1, 256, 0, stream>>>(feat, convw, y, stats);

    pool_kernel<<<512, 256, 0, stream>>>(y, boxes, stats, gnw, gnb, pooled);

    mlp_kernel<<<512, 128, 0, stream>>>(pooled, w1, b1, w2, b2, emb, raw);
}

// Round 4
// 380.655 us; speedup vs baseline: 9.5535x; 9.5535x over previous
//
#include <hip/hip_runtime.h>
#include <math.h>

#define HWq 10000
#define Cq 256

// ---------------------------------------------------------------------------
// Kernel 1: 1x1 conv as fp32 GEMM  y[b,o,p] = sum_c W[o,c] * F[b,c,p]
// Tile: 64 o x 64 p per block (256 threads, 4x4 microtile), K chunks of 16.
// Also accumulates per-batch sum / sumsq of y into stats[0..7], stats[8..15].
// ---------------------------------------------------------------------------
__global__ __launch_bounds__(256) void conv_gemm(const float* __restrict__ feat,
                                                 const float* __restrict__ convw,
                                                 float* __restrict__ y,
                                                 float* __restrict__ stats) {
    __shared__ float As[16][64];   // [k][o]
    __shared__ float Bs[16][64];   // [k][p]
    __shared__ float redbuf[8];

    const int b  = blockIdx.z;
    const int o0 = blockIdx.y * 64;
    const int p0 = blockIdx.x * 64;
    const int t  = threadIdx.x;
    const int tx = t & 15;         // p group
    const int ty = t >> 4;         // o group

    const float* fb = feat + (size_t)b * Cq * HWq;

    float acc[4][4] = {};

    for (int k0 = 0; k0 < Cq; k0 += 16) {
        #pragma unroll
        for (int pass = 0; pass < 4; ++pass) {
            int i = (t >> 4) + pass * 16;   // o 0..63
            int j = t & 15;                 // k 0..15
            As[j][i] = convw[(o0 + i) * Cq + k0 + j];
        }
        #pragma unroll
        for (int pass = 0; pass < 4; ++pass) {
            int r = (t >> 6) + pass * 4;    // k 0..15
            int c = t & 63;                 // p 0..63
            int p = p0 + c;
            if (p > HWq - 1) p = HWq - 1;
            Bs[r][c] = fb[(size_t)(k0 + r) * HWq + p];
        }
        __syncthreads();
        #pragma unroll
        for (int kk = 0; kk < 16; ++kk) {
            const float4 av = *reinterpret_cast<const float4*>(&As[kk][ty * 4]);
            const float4 bv = *reinterpret_cast<const float4*>(&Bs[kk][tx * 4]);
            acc[0][0] += av.x * bv.x; acc[0][1] += av.x * bv.y;
            acc[0][2] += av.x * bv.z; acc[0][3] += av.x * bv.w;
            acc[1][0] += av.y * bv.x; acc[1][1] += av.y * bv.y;
            acc[1][2] += av.y * bv.z; acc[1][3] += av.y * bv.w;
            acc[2][0] += av.z * bv.x; acc[2][1] += av.z * bv.y;
            acc[2][2] += av.z * bv.z; acc[2][3] += av.z * bv.w;
            acc[3][0] += av.w * bv.x; acc[3][1] += av.w * bv.y;
            acc[3][2] += av.w * bv.z; acc[3][3] += av.w * bv.w;
        }
        __syncthreads();
    }

    float lsum = 0.f, lsq = 0.f;
    #pragma unroll
    for (int i = 0; i < 4; ++i) {
        int o = o0 + ty * 4 + i;
        float* yrow = y + (size_t)(b * Cq + o) * HWq;
        #pragma unroll
        for (int j = 0; j < 4; ++j) {
            int p = p0 + tx * 4 + j;
            if (p < HWq) {
                float v = acc[i][j];
                yrow[p] = v;
                lsum += v;
                lsq  += v * v;
            }
        }
    }
    #pragma unroll
    for (int m = 1; m < 64; m <<= 1) {
        lsum += __shfl_xor(lsum, m);
        lsq  += __shfl_xor(lsq, m);
    }
    int wave = t >> 6, lane = t & 63;
    if (lane == 0) { redbuf[wave] = lsum; redbuf[4 + wave] = lsq; }
    __syncthreads();
    if (t == 0) {
        atomicAdd(&stats[b],     redbuf[0] + redbuf[1] + redbuf[2] + redbuf[3]);
        atomicAdd(&stats[8 + b], redbuf[4] + redbuf[5] + redbuf[6] + redbuf[7]);
    }
}

// ---------------------------------------------------------------------------
// Kernel 2: per-(b,c) plane -> in-place 2D inclusive prefix sum of
// silu(gn_norm(y)). One block per plane; plane lives in LDS (40 KB).
// ---------------------------------------------------------------------------
__global__ __launch_bounds__(256) void integral_kernel(float* __restrict__ y,
                                                       const float* __restrict__ stats,
                                                       const float* __restrict__ gnw,
                                                       const float* __restrict__ gnb) {
    __shared__ float Sl[10000];

    const int plane = blockIdx.x;          // b*256 + c
    const int b = plane >> 8;
    const int c = plane & 255;
    const int t = threadIdx.x;
    const int wave = t >> 6;
    const int lane = t & 63;

    const float invM = 1.f / 2560000.f;
    const float mu   = stats[b] * invM;
    const float msq  = stats[8 + b] * invM;
    const float rs   = rsqrtf(msq - mu * mu + 1e-5f);
    const float scale = gnw[c] * rs;
    const float shift = gnb[c] - mu * scale;

    float* yp = y + (size_t)plane * HWq;

    // load + affine + SiLU
    #pragma unroll
    for (int i = 0; i < 40; ++i) {
        int idx = t + i * 256;             // 0..10239, guard
        if (idx < HWq) {
            float v = yp[idx] * scale + shift;
            Sl[idx] = v / (1.f + __expf(-v));
        }
    }
    __syncthreads();

    // row prefix: wave handles rows r = wave, wave+4, ...
    for (int r = wave; r < 100; r += 4) {
        float* row = &Sl[r * 100];
        // chunk A: cols 0..63
        float v = row[lane];
        #pragma unroll
        for (int m = 1; m < 64; m <<= 1) {
            float u = __shfl_up(v, m);
            if (lane >= m) v += u;
        }
        row[lane] = v;
        float total = __shfl(v, 63);
        // chunk B: cols 64..99 (36 elems)
        float w = (lane < 36) ? row[64 + lane] : 0.f;
        #pragma unroll
        for (int m = 1; m < 64; m <<= 1) {
            float u = __shfl_up(w, m);
            if (lane >= m) w += u;
        }
        w += total;
        if (lane < 36) row[64 + lane] = w;
    }
    __syncthreads();

    // col prefix: thread t owns column t (t < 100)
    if (t < 100) {
        float acc = 0.f;
        #pragma unroll 4
        for (int h = 0; h < 100; ++h) {
            acc += Sl[h * 100 + t];
            Sl[h * 100 + t] = acc;
        }
    }
    __syncthreads();

    // store back in place (coalesced)
    #pragma unroll
    for (int i = 0; i < 40; ++i) {
        int idx = t + i * 256;
        if (idx < HWq) yp[idx] = Sl[idx];
    }
}

// ---------------------------------------------------------------------------
// Kernel 3: fused box lookup (4 corners of integral image) + MLP + L2 norm.
// One block per (b,n). 256 threads.
// ---------------------------------------------------------------------------
__global__ __launch_bounds__(256) void head_kernel(const float* __restrict__ S,
                                                   const float* __restrict__ boxes,
                                                   const float* __restrict__ w1,
                                                   const float* __restrict__ b1,
                                                   const float* __restrict__ w2,
                                                   const float* __restrict__ b2,
                                                   float* __restrict__ emb,
                                                   float* __restrict__ raw,
                                                   float* __restrict__ pooled) {
    __shared__ float ps[256];
    __shared__ float hs[128];

    const int bn = blockIdx.x;      // 0..511
    const int b  = bn >> 6;
    const int t  = threadIdx.x;

    const float* bx = boxes + (size_t)bn * 4;
    float bv0 = bx[0], bv1 = bx[1], bv2 = bx[2], bv3 = bx[3];

    float x1f = fminf(bv0, bv2) * 100.f;
    float x2f = fmaxf(bv0, bv2) * 100.f;
    float y1f = fminf(bv1, bv3) * 100.f;
    float y2f = fmaxf(bv1, bv3) * 100.f;
    x1f = fminf(fmaxf(floorf(fminf(fmaxf(x1f, 0.f), 100.f)), 0.f), 100.f);
    x2f = fminf(fmaxf(ceilf (fminf(fmaxf(x2f, 0.f), 100.f)), 0.f), 100.f);
    y1f = fminf(fmaxf(floorf(fminf(fmaxf(y1f, 0.f), 100.f)), 0.f), 100.f);
    y2f = fminf(fmaxf(ceilf (fminf(fmaxf(y2f, 0.f), 100.f)), 0.f), 100.f);
    const int ix1 = (int)x1f, ix2 = (int)x2f;
    const int iy1 = (int)y1f, iy2 = (int)y2f;
    const int cnt = (ix2 - ix1) * (iy2 - iy1);

    // pooled via integral-image corners (thread t = channel)
    float pv = 0.f;
    if (cnt > 0) {
        const float* Sp = S + ((size_t)(b * Cq + t)) * HWq;
        float s = Sp[(iy2 - 1) * 100 + (ix2 - 1)];
        if (iy1 > 0) s -= Sp[(iy1 - 1) * 100 + (ix2 - 1)];
        if (ix1 > 0) s -= Sp[(iy2 - 1) * 100 + (ix1 - 1)];
        if (iy1 > 0 && ix1 > 0) s += Sp[(iy1 - 1) * 100 + (ix1 - 1)];
        pv = s / (float)cnt;
    }
    pooled[(size_t)bn * Cq + t] = pv;
    ps[t] = pv;
    __syncthreads();

    if (t < 128) {
        float a = b1[t];
        #pragma unroll 8
        for (int c = 0; c < 256; ++c) a += ps[c] * w1[c * 128 + t];
        hs[t] = a / (1.f + __expf(-a));
    }
    __syncthreads();

    if (t < 64) {
        float r = b2[t];
        #pragma unroll 8
        for (int h = 0; h < 128; ++h) r += hs[h] * w2[h * 64 + t];
        raw[(size_t)bn * 64 + t] = r;
        float s = r * r;
        #pragma unroll
        for (int m = 1; m < 64; m <<= 1) s += __shfl_xor(s, m);
        float nrm = fmaxf(sqrtf(s), 1e-6f);
        emb[(size_t)bn * 64 + t] = r / nrm;
    }
}

// ---------------------------------------------------------------------------
extern "C" void kernel_launch(void* const* d_in, const int* in_sizes, int n_in,
                              void* d_out, int out_size, void* d_ws, size_t ws_size,
                              hipStream_t stream) {
    const float* feat  = (const float*)d_in[0];
    const float* boxes = (const float*)d_in[1];
    const float* convw = (const float*)d_in[2];
    const float* gnw   = (const float*)d_in[3];
    const float* gnb   = (const float*)d_in[4];
    const float* w1    = (const float*)d_in[5];
    const float* b1    = (const float*)d_in[6];
    const float* w2    = (const float*)d_in[7];
    const float* b2    = (const float*)d_in[8];

    float* out    = (float*)d_out;
    float* emb    = out;             // [8,64,64]   = 32768
    float* raw    = out + 32768;     // [8,64,64]   = 32768
    float* pooled = out + 65536;     // [8,64,256]  = 131072

    float* y     = (float*)d_ws;                                   // 8*256*10000 f32
    float* stats = (float*)((char*)d_ws + (size_t)8 * 256 * 10000 * 4);

    hipMemsetAsync(stats, 0, 16 * sizeof(float), stream);

    dim3 g1((HWq + 63) / 64, 4, 8);
    conv_gemm<<<g1, 256, 0, stream>>>(feat, convw, y, stats);

    integral_kernel<<<2048, 256, 0, stream>>>(y, stats, gnw, gnb);

    head_kernel<<<512, 256, 0, stream>>>(y, boxes, w1, b1, w2, b2, emb, raw, pooled);
}

// Round 5
// 259.985 us; speedup vs baseline: 13.9876x; 1.4641x over previous
//
#include <hip/hip_runtime.h>
#include <math.h>

#define HWq 10000
#define Cq 256   // in channels (K)
#define Oq 256   // out channels (M)

typedef __attribute__((ext_vector_type(8))) short short8v;  // 8 bf16 (4 VGPRs)
typedef __attribute__((ext_vector_type(4))) float f32x4;

__device__ __forceinline__ short f2bf(float f) {
    unsigned u = __float_as_uint(f);
    return (short)((u + 0x7FFFu + ((u >> 16) & 1u)) >> 16);   // RNE truncate
}

// XOR swizzle of 16B units within a 64B k-row: spreads rows across bank quads
__device__ __forceinline__ int swz(int row, int g) {
    return g ^ (row & 3) ^ ((row >> 2) & 1);
}

// ---------------------------------------------------------------------------
// Kernel 1: 1x1 conv as bf16 MFMA GEMM  y[b,o,p] = sum_c W[o,c] * F[b,c,p]
// Block tile 128o x 128p, BK=32, 4 waves (2x2), each wave 64x64 = 4x4 frags
// of mfma_f32_16x16x32_bf16. f32->bf16 conversion fused into LDS staging.
// Also accumulates per-batch sum/sumsq of y into stats[0..7] / stats[8..15].
// ---------------------------------------------------------------------------
__global__ __launch_bounds__(256) void conv_mfma(const float* __restrict__ feat,
                                                 const float* __restrict__ convw,
                                                 float* __restrict__ y,
                                                 float* __restrict__ stats) {
    __shared__ __align__(16) short Albuf[128 * 32];   // [o][k] bf16, swizzled units
    __shared__ __align__(16) short Blbuf[128 * 32];   // [p][k] bf16 (transposed), swizzled
    __shared__ float redbuf[8];

    const int b  = blockIdx.z;
    const int o0 = blockIdx.y * 128;
    const int p0 = blockIdx.x * 128;
    const int t  = threadIdx.x;
    const int w  = t >> 6;          // wave 0..3
    const int l  = t & 63;          // lane
    const int wo = (w >> 1) * 64;   // wave o-offset in tile
    const int wp = (w & 1) * 64;    // wave p-offset in tile

    const float* fb = feat + (size_t)b * Cq * HWq;

    f32x4 acc[4][4];
    #pragma unroll
    for (int i = 0; i < 4; ++i)
        #pragma unroll
        for (int j = 0; j < 4; ++j)
            acc[i][j] = (f32x4){0.f, 0.f, 0.f, 0.f};

    // A staging: chunk c in {t, t+256}: o = c>>2 (0..127), ku = c&3 (16B unit)
    const int oA0 = t >> 2;
    const int oA1 = oA0 + 64;
    const int kuA = t & 3;
    const float* aptr0 = convw + (size_t)(o0 + oA0) * Cq + kuA * 8;
    const float* aptr1 = convw + (size_t)(o0 + oA1) * Cq + kuA * 8;

    // B staging: pass 0/1: p = pass*64 + l, k-row group = w*8 (8 rows)
    int pgB[2];
    #pragma unroll
    for (int pass = 0; pass < 2; ++pass) {
        int pg = p0 + pass * 64 + l;
        pgB[pass] = (pg > HWq - 1) ? (HWq - 1) : pg;
    }

    const int fr_g = l >> 4;   // frag k-unit (0..3)
    const int fr_r = l & 15;   // frag row

    for (int k0 = 0; k0 < Cq; k0 += 32) {
        // ---- stage A (W rows -> bf16, swizzled 16B units)
        {
            const float4 a0 = *(const float4*)(aptr0 + k0);
            const float4 a1 = *(const float4*)(aptr0 + k0 + 4);
            short8v s;
            s[0]=f2bf(a0.x); s[1]=f2bf(a0.y); s[2]=f2bf(a0.z); s[3]=f2bf(a0.w);
            s[4]=f2bf(a1.x); s[5]=f2bf(a1.y); s[6]=f2bf(a1.z); s[7]=f2bf(a1.w);
            *(short8v*)((char*)Albuf + oA0 * 64 + swz(oA0, kuA) * 16) = s;

            const float4 b0 = *(const float4*)(aptr1 + k0);
            const float4 b1 = *(const float4*)(aptr1 + k0 + 4);
            short8v s2;
            s2[0]=f2bf(b0.x); s2[1]=f2bf(b0.y); s2[2]=f2bf(b0.z); s2[3]=f2bf(b0.w);
            s2[4]=f2bf(b1.x); s2[5]=f2bf(b1.y); s2[6]=f2bf(b1.z); s2[7]=f2bf(b1.w);
            *(short8v*)((char*)Albuf + oA1 * 64 + swz(oA1, kuA) * 16) = s2;
        }
        // ---- stage B transposed: wave w loads k-rows k0+w*8..+7, 64 consecutive p
        #pragma unroll
        for (int pass = 0; pass < 2; ++pass) {
            const float* fk = fb + (size_t)(k0 + w * 8) * HWq + pgB[pass];
            short8v s;
            #pragma unroll
            for (int j = 0; j < 8; ++j)
                s[j] = f2bf(fk[(size_t)j * HWq]);
            int p = pass * 64 + l;
            *(short8v*)((char*)Blbuf + p * 64 + swz(p, w) * 16) = s;
        }
        __syncthreads();

        // ---- fragment loads + MFMA
        short8v af[4], bfv[4];
        #pragma unroll
        for (int i = 0; i < 4; ++i) {
            int row = wo + i * 16 + fr_r;
            af[i] = *(const short8v*)((const char*)Albuf + row * 64 + swz(row, fr_g) * 16);
        }
        #pragma unroll
        for (int j = 0; j < 4; ++j) {
            int row = wp + j * 16 + fr_r;
            bfv[j] = *(const short8v*)((const char*)Blbuf + row * 64 + swz(row, fr_g) * 16);
        }
        #pragma unroll
        for (int i = 0; i < 4; ++i)
            #pragma unroll
            for (int j = 0; j < 4; ++j)
                acc[i][j] = __builtin_amdgcn_mfma_f32_16x16x32_bf16(af[i], bfv[j], acc[i][j], 0, 0, 0);
        __syncthreads();
    }

    // ---- epilogue: store y + per-batch stats
    float lsum = 0.f, lsq = 0.f;
    #pragma unroll
    for (int i = 0; i < 4; ++i) {
        const int obase = o0 + wo + i * 16 + (l >> 4) * 4;
        #pragma unroll
        for (int j = 0; j < 4; ++j) {
            const int p = p0 + wp + j * 16 + (l & 15);
            if (p < HWq) {
                #pragma unroll
                for (int r = 0; r < 4; ++r) {
                    float v = acc[i][j][r];
                    y[((size_t)(b * Oq + obase + r)) * HWq + p] = v;
                    lsum += v;
                    lsq  += v * v;
                }
            }
        }
    }
    #pragma unroll
    for (int m = 1; m < 64; m <<= 1) {
        lsum += __shfl_xor(lsum, m);
        lsq  += __shfl_xor(lsq, m);
    }
    if (l == 0) { redbuf[w] = lsum; redbuf[4 + w] = lsq; }
    __syncthreads();
    if (t == 0) {
        atomicAdd(&stats[b],     redbuf[0] + redbuf[1] + redbuf[2] + redbuf[3]);
        atomicAdd(&stats[8 + b], redbuf[4] + redbuf[5] + redbuf[6] + redbuf[7]);
    }
}

// ---------------------------------------------------------------------------
// Kernel 2: per-(b,c) plane -> in-place 2D inclusive prefix sum of
// silu(gn_norm(y)). One block per plane; plane lives in LDS (40 KB).
// ---------------------------------------------------------------------------
__global__ __launch_bounds__(256) void integral_kernel(float* __restrict__ y,
                                                       const float* __restrict__ stats,
                                                       const float* __restrict__ gnw,
                                                       const float* __restrict__ gnb) {
    __shared__ float Sl[10000];

    const int plane = blockIdx.x;          // b*256 + c
    const int b = plane >> 8;
    const int c = plane & 255;
    const int t = threadIdx.x;
    const int wave = t >> 6;
    const int lane = t & 63;

    const float invM = 1.f / 2560000.f;
    const float mu   = stats[b] * invM;
    const float msq  = stats[8 + b] * invM;
    const float rs   = rsqrtf(msq - mu * mu + 1e-5f);
    const float scale = gnw[c] * rs;
    const float shift = gnb[c] - mu * scale;

    float* yp = y + (size_t)plane * HWq;

    #pragma unroll
    for (int i = 0; i < 40; ++i) {
        int idx = t + i * 256;
        if (idx < HWq) {
            float v = yp[idx] * scale + shift;
            Sl[idx] = v / (1.f + __expf(-v));
        }
    }
    __syncthreads();

    for (int r = wave; r < 100; r += 4) {
        float* row = &Sl[r * 100];
        float v = row[lane];
        #pragma unroll
        for (int m = 1; m < 64; m <<= 1) {
            float u = __shfl_up(v, m);
            if (lane >= m) v += u;
        }
        row[lane] = v;
        float total = __shfl(v, 63);
        float w = (lane < 36) ? row[64 + lane] : 0.f;
        #pragma unroll
        for (int m = 1; m < 64; m <<= 1) {
            float u = __shfl_up(w, m);
            if (lane >= m) w += u;
        }
        w += total;
        if (lane < 36) row[64 + lane] = w;
    }
    __syncthreads();

    if (t < 100) {
        float acc = 0.f;
        #pragma unroll 4
        for (int h = 0; h < 100; ++h) {
            acc += Sl[h * 100 + t];
            Sl[h * 100 + t] = acc;
        }
    }
    __syncthreads();

    #pragma unroll
    for (int i = 0; i < 40; ++i) {
        int idx = t + i * 256;
        if (idx < HWq) yp[idx] = Sl[idx];
    }
}

// ---------------------------------------------------------------------------
// Kernel 3: fused box lookup (4 corners of integral image) + MLP + L2 norm.
// One block per (b,n). 256 threads.
// ---------------------------------------------------------------------------
__global__ __launch_bounds__(256) void head_kernel(const float* __restrict__ S,
                                                   const float* __restrict__ boxes,
                                                   const float* __restrict__ w1,
                                                   const float* __restrict__ b1,
                                                   const float* __restrict__ w2,
                                                   const float* __restrict__ b2,
                                                   float* __restrict__ emb,
                                                   float* __restrict__ raw,
                                                   float* __restrict__ pooled) {
    __shared__ float ps[256];
    __shared__ float hs[128];

    const int bn = blockIdx.x;      // 0..511
    const int b  = bn >> 6;
    const int t  = threadIdx.x;

    const float* bx = boxes + (size_t)bn * 4;
    float bv0 = bx[0], bv1 = bx[1], bv2 = bx[2], bv3 = bx[3];

    float x1f = fminf(bv0, bv2) * 100.f;
    float x2f = fmaxf(bv0, bv2) * 100.f;
    float y1f = fminf(bv1, bv3) * 100.f;
    float y2f = fmaxf(bv1, bv3) * 100.f;
    x1f = fminf(fmaxf(floorf(fminf(fmaxf(x1f, 0.f), 100.f)), 0.f), 100.f);
    x2f = fminf(fmaxf(ceilf (fminf(fmaxf(x2f, 0.f), 100.f)), 0.f), 100.f);
    y1f = fminf(fmaxf(floorf(fminf(fmaxf(y1f, 0.f), 100.f)), 0.f), 100.f);
    y2f = fminf(fmaxf(ceilf (fminf(fmaxf(y2f, 0.f), 100.f)), 0.f), 100.f);
    const int ix1 = (int)x1f, ix2 = (int)x2f;
    const int iy1 = (int)y1f, iy2 = (int)y2f;
    const int cnt = (ix2 - ix1) * (iy2 - iy1);

    float pv = 0.f;
    if (cnt > 0) {
        const float* Sp = S + ((size_t)(b * Cq + t)) * HWq;
        float s = Sp[(iy2 - 1) * 100 + (ix2 - 1)];
        if (iy1 > 0) s -= Sp[(iy1 - 1) * 100 + (ix2 - 1)];
        if (ix1 > 0) s -= Sp[(iy2 - 1) * 100 + (ix1 - 1)];
        if (iy1 > 0 && ix1 > 0) s += Sp[(iy1 - 1) * 100 + (ix1 - 1)];
        pv = s / (float)cnt;
    }
    pooled[(size_t)bn * Cq + t] = pv;
    ps[t] = pv;
    __syncthreads();

    if (t < 128) {
        float a = b1[t];
        #pragma unroll 8
        for (int c = 0; c < 256; ++c) a += ps[c] * w1[c * 128 + t];
        hs[t] = a / (1.f + __expf(-a));
    }
    __syncthreads();

    if (t < 64) {
        float r = b2[t];
        #pragma unroll 8
        for (int h = 0; h < 128; ++h) r += hs[h] * w2[h * 64 + t];
        raw[(size_t)bn * 64 + t] = r;
        float s = r * r;
        #pragma unroll
        for (int m = 1; m < 64; m <<= 1) s += __shfl_xor(s, m);
        float nrm = fmaxf(sqrtf(s), 1e-6f);
        emb[(size_t)bn * 64 + t] = r / nrm;
    }
}

// ---------------------------------------------------------------------------
extern "C" void kernel_launch(void* const* d_in, const int* in_sizes, int n_in,
                              void* d_out, int out_size, void* d_ws, size_t ws_size,
                              hipStream_t stream) {
    const float* feat  = (const float*)d_in[0];
    const float* boxes = (const float*)d_in[1];
    const float* convw = (const float*)d_in[2];
    const float* gnw   = (const float*)d_in[3];
    const float* gnb   = (const float*)d_in[4];
    const float* w1    = (const float*)d_in[5];
    const float* b1    = (const float*)d_in[6];
    const float* w2    = (const float*)d_in[7];
    const float* b2    = (const float*)d_in[8];

    float* out    = (float*)d_out;
    float* emb    = out;             // [8,64,64]   = 32768
    float* raw    = out + 32768;     // [8,64,64]   = 32768
    float* pooled = out + 65536;     // [8,64,256]  = 131072

    float* y     = (float*)d_ws;                                   // 8*256*10000 f32
    float* stats = (float*)((char*)d_ws + (size_t)8 * 256 * 10000 * 4);

    hipMemsetAsync(stats, 0, 16 * sizeof(float), stream);

    dim3 g1((HWq + 127) / 128, 2, 8);   // 79 x 2 x 8 = 1264 blocks
    conv_mfma<<<g1, 256, 0, stream>>>(feat, convw, y, stats);

    integral_kernel<<<2048, 256, 0, stream>>>(y, stats, gnw, gnb);

    head_kernel<<<512, 256, 0, stream>>>(y, boxes, w1, b1, w2, b2, emb, raw, pooled);
}

// Round 9
// 243.056 us; speedup vs baseline: 14.9619x; 1.0696x over previous
//
#include <hip/hip_runtime.h>
#include <math.h>

#define HWq 10000
#define Cq 256   // in channels (K)
#define Oq 256   // out channels (M)

typedef __attribute__((ext_vector_type(8))) short short8v;           // 8 bf16
typedef __attribute__((ext_vector_type(8))) unsigned short ushort8v; // 8 bf16 bits
typedef __attribute__((ext_vector_type(4))) float f32x4;

__device__ __forceinline__ short f2bf(float f) {
    unsigned u = __float_as_uint(f);
    return (short)((u + 0x7FFFu + ((u >> 16) & 1u)) >> 16);   // RNE
}
__device__ __forceinline__ float bf2f(unsigned short u) {
    return __uint_as_float((unsigned)u << 16);
}

// XOR swizzle of 16B units within a 64B k-row
__device__ __forceinline__ int swz(int row, int g) {
    return g ^ (row & 3) ^ ((row >> 2) & 1);
}

// ---------------------------------------------------------------------------
// Kernel 1: 1x1 conv as bf16 MFMA GEMM, y stored as bf16.
// Block tile 128o x 128p, BK=32, 4 waves (2x2), reg-prefetch double pipeline.
// Accumulates per-batch sum/sumsq (f32) into stats[0..7] / stats[8..15].
// ---------------------------------------------------------------------------
__global__ __launch_bounds__(256) void conv_mfma(const float* __restrict__ feat,
                                                 const float* __restrict__ convw,
                                                 unsigned short* __restrict__ y,
                                                 float* __restrict__ stats) {
    __shared__ __align__(16) short Albuf[128 * 32];   // [o][k] bf16, swizzled
    __shared__ __align__(16) short Blbuf[128 * 32];   // [p][k] bf16, swizzled
    __shared__ float redbuf[8];

    const int b  = blockIdx.z;
    const int o0 = blockIdx.y * 128;
    const int p0 = blockIdx.x * 128;
    const int t  = threadIdx.x;
    const int w  = t >> 6;
    const int l  = t & 63;
    const int wo = (w >> 1) * 64;
    const int wp = (w & 1) * 64;

    const float* fb = feat + (size_t)b * Cq * HWq;

    f32x4 acc[4][4];
    #pragma unroll
    for (int i = 0; i < 4; ++i)
        #pragma unroll
        for (int j = 0; j < 4; ++j)
            acc[i][j] = (f32x4){0.f, 0.f, 0.f, 0.f};

    const int oA0 = t >> 2;
    const int oA1 = oA0 + 64;
    const int kuA = t & 3;
    const float* aptr0 = convw + (size_t)(o0 + oA0) * Cq + kuA * 8;
    const float* aptr1 = convw + (size_t)(o0 + oA1) * Cq + kuA * 8;

    int pgB[2];
    #pragma unroll
    for (int pass = 0; pass < 2; ++pass) {
        int pg = p0 + pass * 64 + l;
        pgB[pass] = (pg > HWq - 1) ? (HWq - 1) : pg;
    }

    const int fr_g = l >> 4;
    const int fr_r = l & 15;

    float4 ra0, ra1, ra2, ra3;
    float  rb[2][8];

    auto LOADG = [&](int k0) {
        ra0 = *(const float4*)(aptr0 + k0);
        ra1 = *(const float4*)(aptr0 + k0 + 4);
        ra2 = *(const float4*)(aptr1 + k0);
        ra3 = *(const float4*)(aptr1 + k0 + 4);
        #pragma unroll
        for (int pass = 0; pass < 2; ++pass) {
            const float* fk = fb + (size_t)(k0 + w * 8) * HWq + pgB[pass];
            #pragma unroll
            for (int jj = 0; jj < 8; ++jj)
                rb[pass][jj] = fk[(size_t)jj * HWq];
        }
    };

    LOADG(0);

    for (int k0 = 0; k0 < Cq; k0 += 32) {
        if (k0) __syncthreads();               // LDS reads of prev step done

        // ---- LDS write from regs (f32 -> bf16)
        {
            short8v s;
            s[0]=f2bf(ra0.x); s[1]=f2bf(ra0.y); s[2]=f2bf(ra0.z); s[3]=f2bf(ra0.w);
            s[4]=f2bf(ra1.x); s[5]=f2bf(ra1.y); s[6]=f2bf(ra1.z); s[7]=f2bf(ra1.w);
            *(short8v*)((char*)Albuf + oA0 * 64 + swz(oA0, kuA) * 16) = s;
            short8v s2;
            s2[0]=f2bf(ra2.x); s2[1]=f2bf(ra2.y); s2[2]=f2bf(ra2.z); s2[3]=f2bf(ra2.w);
            s2[4]=f2bf(ra3.x); s2[5]=f2bf(ra3.y); s2[6]=f2bf(ra3.z); s2[7]=f2bf(ra3.w);
            *(short8v*)((char*)Albuf + oA1 * 64 + swz(oA1, kuA) * 16) = s2;
            #pragma unroll
            for (int pass = 0; pass < 2; ++pass) {
                short8v sb;
                #pragma unroll
                for (int jj = 0; jj < 8; ++jj) sb[jj] = f2bf(rb[pass][jj]);
                int p = pass * 64 + l;
                *(short8v*)((char*)Blbuf + p * 64 + swz(p, w) * 16) = sb;
            }
        }
        __syncthreads();

        if (k0 < Cq - 32) LOADG(k0 + 32);      // prefetch next chunk (hides under MFMA)

        short8v af[4], bfv[4];
        #pragma unroll
        for (int i = 0; i < 4; ++i) {
            int row = wo + i * 16 + fr_r;
            af[i] = *(const short8v*)((const char*)Albuf + row * 64 + swz(row, fr_g) * 16);
        }
        #pragma unroll
        for (int j = 0; j < 4; ++j) {
            int row = wp + j * 16 + fr_r;
            bfv[j] = *(const short8v*)((const char*)Blbuf + row * 64 + swz(row, fr_g) * 16);
        }
        #pragma unroll
        for (int i = 0; i < 4; ++i)
            #pragma unroll
            for (int j = 0; j < 4; ++j)
                acc[i][j] = __builtin_amdgcn_mfma_f32_16x16x32_bf16(af[i], bfv[j], acc[i][j], 0, 0, 0);
    }

    // ---- epilogue: bf16 y store + f32 stats
    float lsum = 0.f, lsq = 0.f;
    #pragma unroll
    for (int i = 0; i < 4; ++i) {
        const int obase = o0 + wo + i * 16 + (l >> 4) * 4;
        #pragma unroll
        for (int j = 0; j < 4; ++j) {
            const int p = p0 + wp + j * 16 + (l & 15);
            if (p < HWq) {
                #pragma unroll
                for (int r = 0; r < 4; ++r) {
                    float v = acc[i][j][r];
                    y[((size_t)(b * Oq + obase + r)) * HWq + p] = (unsigned short)f2bf(v);
                    lsum += v;
                    lsq  += v * v;
                }
            }
        }
    }
    #pragma unroll
    for (int m = 1; m < 64; m <<= 1) {
        lsum += __shfl_xor(lsum, m);
        lsq  += __shfl_xor(lsq, m);
    }
    if (l == 0) { redbuf[w] = lsum; redbuf[4 + w] = lsq; }
    __syncthreads();
    if (t == 0) {
        atomicAdd(&stats[b],     redbuf[0] + redbuf[1] + redbuf[2] + redbuf[3]);
        atomicAdd(&stats[8 + b], redbuf[4] + redbuf[5] + redbuf[6] + redbuf[7]);
    }
}

// ---------------------------------------------------------------------------
// Kernel 2: per-(b,c) plane: normalize+SiLU -> 2D prefix sum in LDS ->
// directly pool all 64 boxes of b (4 corner lanes per box) -> pooled[b,n,c].
// No integral image ever touches HBM.
// ---------------------------------------------------------------------------
__global__ __launch_bounds__(256) void integral_pool(const unsigned short* __restrict__ y,
                                                     const float* __restrict__ boxes,
                                                     const float* __restrict__ stats,
                                                     const float* __restrict__ gnw,
                                                     const float* __restrict__ gnb,
                                                     float* __restrict__ pooled) {
    __shared__ float Sl[10000];

    const int plane = blockIdx.x;          // b*256 + c
    const int b = plane >> 8;
    const int c = plane & 255;
    const int t = threadIdx.x;
    const int wave = t >> 6;
    const int lane = t & 63;

    const float invM = 1.f / 2560000.f;
    const float mu   = stats[b] * invM;
    const float msq  = stats[8 + b] * invM;
    const float rs   = rsqrtf(msq - mu * mu + 1e-5f);
    const float scale = gnw[c] * rs;
    const float shift = gnb[c] - mu * scale;

    const ushort8v* yp8 = (const ushort8v*)(y + (size_t)plane * HWq);

    // load bf16x8 + affine + SiLU
    #pragma unroll
    for (int i = 0; i < 5; ++i) {
        int chunk = t + i * 256;           // 1250 chunks of 8
        if (chunk < 1250) {
            ushort8v u = yp8[chunk];
            float* dst = &Sl[chunk * 8];
            #pragma unroll
            for (int k = 0; k < 8; ++k) {
                float v = bf2f(u[k]) * scale + shift;
                dst[k] = v / (1.f + __expf(-v));
            }
        }
    }
    __syncthreads();

    // row prefix: wave handles rows r = wave, wave+4, ...
    for (int r = wave; r < 100; r += 4) {
        float* row = &Sl[r * 100];
        float v = row[lane];
        #pragma unroll
        for (int m = 1; m < 64; m <<= 1) {
            float u = __shfl_up(v, m);
            if (lane >= m) v += u;
        }
        row[lane] = v;
        float total = __shfl(v, 63);
        float w2 = (lane < 36) ? row[64 + lane] : 0.f;
        #pragma unroll
        for (int m = 1; m < 64; m <<= 1) {
            float u = __shfl_up(w2, m);
            if (lane >= m) w2 += u;
        }
        w2 += total;
        if (lane < 36) row[64 + lane] = w2;
    }
    __syncthreads();

    // col prefix, 4-way segmented: wave w owns rows [25w, 25w+25)
    {
        const int r0 = wave * 25;
        float accA = 0.f, accB = 0.f;
        const bool hasB = lane < 36;
        const int cA = lane, cB = 64 + lane;
        for (int r = r0; r < r0 + 25; ++r) {
            accA += Sl[r * 100 + cA];
            Sl[r * 100 + cA] = accA;
            if (hasB) {
                accB += Sl[r * 100 + cB];
                Sl[r * 100 + cB] = accB;
            }
        }
    }
    __syncthreads();
    {
        // read segment totals (rows 24,49,74) BEFORE modification
        const int cA = lane, cB = 64 + lane;
        const bool hasB = lane < 36;
        float s0A = Sl[24 * 100 + cA], s1A = Sl[49 * 100 + cA], s2A = Sl[74 * 100 + cA];
        float s0B = 0.f, s1B = 0.f, s2B = 0.f;
        if (hasB) { s0B = Sl[24 * 100 + cB]; s1B = Sl[49 * 100 + cB]; s2B = Sl[74 * 100 + cB]; }
        float offA = (wave >= 1 ? s0A : 0.f) + (wave >= 2 ? s1A : 0.f) + (wave >= 3 ? s2A : 0.f);
        float offB = (wave >= 1 ? s0B : 0.f) + (wave >= 2 ? s1B : 0.f) + (wave >= 3 ? s2B : 0.f);
        __syncthreads();
        if (wave >= 1) {
            const int r0 = wave * 25;
            for (int r = r0; r < r0 + 25; ++r) {
                Sl[r * 100 + cA] += offA;
                if (hasB) Sl[r * 100 + cB] += offB;
            }
        }
    }
    __syncthreads();

    // box pooling: 4 lanes per box (one corner each), 16 boxes per wave
    {
        const int grp = lane >> 2;          // 0..15
        const int j   = lane & 3;           // corner id
        const int n   = wave * 16 + grp;    // 0..63
        const float4 bx = *(const float4*)(boxes + ((size_t)b * 64 + n) * 4);

        float x1f = fminf(bx.x, bx.z) * 100.f;
        float x2f = fmaxf(bx.x, bx.z) * 100.f;
        float y1f = fminf(bx.y, bx.w) * 100.f;
        float y2f = fmaxf(bx.y, bx.w) * 100.f;
        x1f = fminf(fmaxf(floorf(fminf(fmaxf(x1f, 0.f), 100.f)), 0.f), 100.f);
        x2f = fminf(fmaxf(ceilf (fminf(fmaxf(x2f, 0.f), 100.f)), 0.f), 100.f);
        y1f = fminf(fmaxf(floorf(fminf(fmaxf(y1f, 0.f), 100.f)), 0.f), 100.f);
        y2f = fminf(fmaxf(ceilf (fminf(fmaxf(y2f, 0.f), 100.f)), 0.f), 100.f);
        const int ix1 = (int)x1f, ix2 = (int)x2f;
        const int iy1 = (int)y1f, iy2 = (int)y2f;
        const int cnt = (ix2 - ix1) * (iy2 - iy1);

        const int hy = (j & 2) ? iy2 - 1 : iy1 - 1;
        const int hx = (j & 1) ? ix2 - 1 : ix1 - 1;
        float v = 0.f;
        if (hy >= 0 && hx >= 0) v = Sl[hy * 100 + hx];
        if (j == 1 || j == 2) v = -v;
        v += __shfl_xor(v, 1);
        v += __shfl_xor(v, 2);
        if (j == 0)
            pooled[((size_t)b * 64 + n) * Cq + c] = (cnt > 0) ? v / (float)cnt : 0.f;
    }
}

// ---------------------------------------------------------------------------
// Kernel 3: MLP (256->128 SiLU ->64) + L2 normalize. One block per (b,n).
// ---------------------------------------------------------------------------
__global__ __launch_bounds__(128) void mlp_kernel(const float* __restrict__ pooled,
                                                  const float* __restrict__ w1,
                                                  const float* __restrict__ b1,
                                                  const float* __restrict__ w2,
                                                  const float* __restrict__ b2,
                                                  float* __restrict__ emb,
                                                  float* __restrict__ raw) {
    __shared__ float ps[256];
    __shared__ float hs[128];
    const int bn = blockIdx.x;
    const int t  = threadIdx.x;

    ps[t]       = pooled[(size_t)bn * 256 + t];
    ps[t + 128] = pooled[(size_t)bn * 256 + t + 128];
    __syncthreads();

    float a = b1[t];
    #pragma unroll 8
    for (int c = 0; c < 256; ++c) a += ps[c] * w1[c * 128 + t];
    hs[t] = a / (1.f + __expf(-a));
    __syncthreads();

    if (t < 64) {
        float r = b2[t];
        #pragma unroll 8
        for (int h = 0; h < 128; ++h) r += hs[h] * w2[h * 64 + t];
        raw[(size_t)bn * 64 + t] = r;
        float s = r * r;
        #pragma unroll
        for (int m = 1; m < 64; m <<= 1) s += __shfl_xor(s, m);
        float nrm = fmaxf(sqrtf(s), 1e-6f);
        emb[(size_t)bn * 64 + t] = r / nrm;
    }
}

// ---------------------------------------------------------------------------
extern "C" void kernel_launch(void* const* d_in, const int* in_sizes, int n_in,
                              void* d_out, int out_size, void* d_ws, size_t ws_size,
                              hipStream_t stream) {
    const float* feat  = (const float*)d_in[0];
    const float* boxes = (const float*)d_in[1];
    const float* convw = (const float*)d_in[2];
    const float* gnw   = (const float*)d_in[3];
    const float* gnb   = (const float*)d_in[4];
    const float* w1    = (const float*)d_in[5];
    const float* b1    = (const float*)d_in[6];
    const float* w2    = (const float*)d_in[7];
    const float* b2    = (const float*)d_in[8];

    float* out    = (float*)d_out;
    float* emb    = out;             // [8,64,64]   = 32768
    float* raw    = out + 32768;     // [8,64,64]   = 32768
    float* pooled = out + 65536;     // [8,64,256]  = 131072

    unsigned short* y = (unsigned short*)d_ws;                     // 8*256*10000 bf16
    float* stats = (float*)((char*)d_ws + (size_t)8 * 256 * 10000 * 2);

    hipMemsetAsync(stats, 0, 16 * sizeof(float), stream);

    dim3 g1((HWq + 127) / 128, 2, 8);   // 79 x 2 x 8
    conv_mfma<<<g1, 256, 0, stream>>>(feat, convw, y, stats);

    integral_pool<<<2048, 256, 0, stream>>>(y, boxes, stats, gnw, gnb, pooled);

    mlp_kernel<<<512, 128, 0, stream>>>(pooled, w1, b1, w2, b2, emb, raw);
}

// Round 11
// 230.264 us; speedup vs baseline: 15.7931x; 1.0556x over previous
//
#include <hip/hip_runtime.h>
#include <math.h>

#define HWq 10000
#define Cq 256   // in channels (K)
#define Oq 256   // out channels (M)

typedef __attribute__((ext_vector_type(8))) short short8v;           // 8 bf16
typedef __attribute__((ext_vector_type(4))) float f32x4;

__device__ __forceinline__ short f2bf(float f) {
    unsigned u = __float_as_uint(f);
    return (short)((u + 0x7FFFu + ((u >> 16) & 1u)) >> 16);   // RNE
}
__device__ __forceinline__ float bf2f(unsigned short u) {
    return __uint_as_float((unsigned)u << 16);
}

// XOR swizzle of 16B units within a 64B k-row
__device__ __forceinline__ int swz(int row, int g) {
    return g ^ (row & 3) ^ ((row >> 2) & 1);
}

// ---------------------------------------------------------------------------
// Kernel 1: 1x1 conv as bf16 MFMA GEMM, y stored as bf16.
// Block tile 128o x 128p, BK=32, 4 waves (2x2).
// Double-buffered LDS: ONE barrier per K-step; reg-prefetch of tile k+2.
// Accumulates per-batch sum/sumsq (f32) into stats[0..7] / stats[8..15].
// ---------------------------------------------------------------------------
__global__ __launch_bounds__(256) void conv_mfma(const float* __restrict__ feat,
                                                 const float* __restrict__ convw,
                                                 unsigned short* __restrict__ y,
                                                 float* __restrict__ stats) {
    __shared__ __align__(16) short Al[2][128 * 32];   // [o][k] bf16, swizzled
    __shared__ __align__(16) short Bl[2][128 * 32];   // [p][k] bf16, swizzled
    __shared__ float redbuf[8];

    const int b  = blockIdx.z;
    const int o0 = blockIdx.y * 128;
    const int p0 = blockIdx.x * 128;
    const int t  = threadIdx.x;
    const int w  = t >> 6;
    const int l  = t & 63;
    const int wo = (w >> 1) * 64;
    const int wp = (w & 1) * 64;

    const float* fb = feat + (size_t)b * Cq * HWq;

    f32x4 acc[4][4];
    #pragma unroll
    for (int i = 0; i < 4; ++i)
        #pragma unroll
        for (int j = 0; j < 4; ++j)
            acc[i][j] = (f32x4){0.f, 0.f, 0.f, 0.f};

    const int oA0 = t >> 2;
    const int oA1 = oA0 + 64;
    const int kuA = t & 3;
    const float* aptr0 = convw + (size_t)(o0 + oA0) * Cq + kuA * 8;
    const float* aptr1 = convw + (size_t)(o0 + oA1) * Cq + kuA * 8;

    int pgB[2];
    #pragma unroll
    for (int pass = 0; pass < 2; ++pass) {
        int pg = p0 + pass * 64 + l;
        pgB[pass] = (pg > HWq - 1) ? (HWq - 1) : pg;
    }

    const int fr_g = l >> 4;
    const int fr_r = l & 15;

    float4 ra0, ra1, ra2, ra3;
    float  rb[2][8];

    auto LOADG = [&](int k0) {
        ra0 = *(const float4*)(aptr0 + k0);
        ra1 = *(const float4*)(aptr0 + k0 + 4);
        ra2 = *(const float4*)(aptr1 + k0);
        ra3 = *(const float4*)(aptr1 + k0 + 4);
        #pragma unroll
        for (int pass = 0; pass < 2; ++pass) {
            const float* fk = fb + (size_t)(k0 + w * 8) * HWq + pgB[pass];
            #pragma unroll
            for (int jj = 0; jj < 8; ++jj)
                rb[pass][jj] = fk[(size_t)jj * HWq];
        }
    };

    auto WRITE = [&](int bi) {
        short8v s;
        s[0]=f2bf(ra0.x); s[1]=f2bf(ra0.y); s[2]=f2bf(ra0.z); s[3]=f2bf(ra0.w);
        s[4]=f2bf(ra1.x); s[5]=f2bf(ra1.y); s[6]=f2bf(ra1.z); s[7]=f2bf(ra1.w);
        *(short8v*)((char*)Al[bi] + oA0 * 64 + swz(oA0, kuA) * 16) = s;
        short8v s2;
        s2[0]=f2bf(ra2.x); s2[1]=f2bf(ra2.y); s2[2]=f2bf(ra2.z); s2[3]=f2bf(ra2.w);
        s2[4]=f2bf(ra3.x); s2[5]=f2bf(ra3.y); s2[6]=f2bf(ra3.z); s2[7]=f2bf(ra3.w);
        *(short8v*)((char*)Al[bi] + oA1 * 64 + swz(oA1, kuA) * 16) = s2;
        #pragma unroll
        for (int pass = 0; pass < 2; ++pass) {
            short8v sb;
            #pragma unroll
            for (int jj = 0; jj < 8; ++jj) sb[jj] = f2bf(rb[pass][jj]);
            int p = pass * 64 + l;
            *(short8v*)((char*)Bl[bi] + p * 64 + swz(p, w) * 16) = sb;
        }
    };

    LOADG(0);
    WRITE(0);
    LOADG(32);                 // tile 1 into regs
    __syncthreads();           // buf0 ready

    int cur = 0;
    for (int k0 = 0; k0 < Cq; k0 += 32) {
        // fragment reads from current buffer (issued first so MFMA waits only on these)
        short8v af[4], bfv[4];
        #pragma unroll
        for (int i = 0; i < 4; ++i) {
            int row = wo + i * 16 + fr_r;
            af[i] = *(const short8v*)((const char*)Al[cur] + row * 64 + swz(row, fr_g) * 16);
        }
        #pragma unroll
        for (int j = 0; j < 4; ++j) {
            int row = wp + j * 16 + fr_r;
            bfv[j] = *(const short8v*)((const char*)Bl[cur] + row * 64 + swz(row, fr_g) * 16);
        }
        // stage next tile into the other buffer, prefetch tile k0+64
        if (k0 + 32 < Cq) {
            WRITE(cur ^ 1);
            if (k0 + 64 < Cq) LOADG(k0 + 64);
        }
        #pragma unroll
        for (int i = 0; i < 4; ++i)
            #pragma unroll
            for (int j = 0; j < 4; ++j)
                acc[i][j] = __builtin_amdgcn_mfma_f32_16x16x32_bf16(af[i], bfv[j], acc[i][j], 0, 0, 0);
        __syncthreads();       // one barrier per K-step
        cur ^= 1;
    }

    // ---- epilogue: bf16 y store + f32 stats
    float lsum = 0.f, lsq = 0.f;
    #pragma unroll
    for (int i = 0; i < 4; ++i) {
        const int obase = o0 + wo + i * 16 + (l >> 4) * 4;
        #pragma unroll
        for (int j = 0; j < 4; ++j) {
            const int p = p0 + wp + j * 16 + (l & 15);
            if (p < HWq) {
                #pragma unroll
                for (int r = 0; r < 4; ++r) {
                    float v = acc[i][j][r];
                    y[((size_t)(b * Oq + obase + r)) * HWq + p] = (unsigned short)f2bf(v);
                    lsum += v;
                    lsq  += v * v;
                }
            }
        }
    }
    #pragma unroll
    for (int m = 1; m < 64; m <<= 1) {
        lsum += __shfl_xor(lsum, m);
        lsq  += __shfl_xor(lsq, m);
    }
    if (l == 0) { redbuf[w] = lsum; redbuf[4 + w] = lsq; }
    __syncthreads();
    if (t == 0) {
        atomicAdd(&stats[b],     redbuf[0] + redbuf[1] + redbuf[2] + redbuf[3]);
        atomicAdd(&stats[8 + b], redbuf[4] + redbuf[5] + redbuf[6] + redbuf[7]);
    }
}

// ---------------------------------------------------------------------------
// Kernel 2: per-(b,c) plane. Each wave loads its own rows from global,
// normalizes+SiLUs in-register, does a 50-lane pair-scan (row prefix along x),
// writes prefix to LDS. Pooling = per-box row-range sums (no column scan).
// ---------------------------------------------------------------------------
__global__ __launch_bounds__(256) void integral_pool(const unsigned short* __restrict__ y,
                                                     const float* __restrict__ boxes,
                                                     const float* __restrict__ stats,
                                                     const float* __restrict__ gnw,
                                                     const float* __restrict__ gnb,
                                                     float* __restrict__ pooled) {
    __shared__ float Sl[10000];          // row-prefix values

    const int plane = blockIdx.x;        // b*256 + c
    const int b = plane >> 8;
    const int c = plane & 255;
    const int wave = threadIdx.x >> 6;
    const int lane = threadIdx.x & 63;

    const float invM = 1.f / 2560000.f;
    const float mu   = stats[b] * invM;
    const float msq  = stats[8 + b] * invM;
    const float rs   = rsqrtf(msq - mu * mu + 1e-5f);
    const float scale = gnw[c] * rs;
    const float shift = gnb[c] - mu * scale;

    const unsigned short* yp = y + (size_t)plane * HWq;

    // row prefix: wave owns rows wave+4i, i=0..24; 2-row ILP unroll.
    for (int i = 0; i < 25; i += 2) {
        const int r0 = wave + 4 * i;
        const int r1 = r0 + 4;
        const bool has1 = (i + 1) < 25;
        float a0 = 0.f, b0 = 0.f, a1 = 0.f, b1 = 0.f;
        if (lane < 50) {
            ushort2 u0 = *(const ushort2*)(yp + r0 * 100 + 2 * lane);
            float v0 = bf2f(u0.x) * scale + shift;
            float v1 = bf2f(u0.y) * scale + shift;
            a0 = v0 / (1.f + __expf(-v0));
            b0 = v1 / (1.f + __expf(-v1));
            if (has1) {
                ushort2 u1 = *(const ushort2*)(yp + r1 * 100 + 2 * lane);
                float w0 = bf2f(u1.x) * scale + shift;
                float w1 = bf2f(u1.y) * scale + shift;
                a1 = w0 / (1.f + __expf(-w0));
                b1 = w1 / (1.f + __expf(-w1));
            }
        }
        float p0 = a0 + b0;
        float p1 = a1 + b1;
        #pragma unroll
        for (int m = 1; m < 64; m <<= 1) {
            float t0 = __shfl_up(p0, m);
            float t1 = __shfl_up(p1, m);
            if (lane >= m) { p0 += t0; p1 += t1; }
        }
        if (lane < 50) {
            float2 o0 = {p0 - b0, p0};            // inclusive prefix at x=2l, 2l+1
            *(float2*)(&Sl[r0 * 100 + 2 * lane]) = o0;
            if (has1) {
                float2 o1 = {p1 - b1, p1};
                *(float2*)(&Sl[r1 * 100 + 2 * lane]) = o1;
            }
        }
    }
    __syncthreads();

    // pooling: 4 lanes per box; lane j sums rows iy1+j, step 4
    {
        const int grp = lane >> 2;           // 0..15
        const int j   = lane & 3;
        const int n   = wave * 16 + grp;     // 0..63
        const float4 bx = *(const float4*)(boxes + ((size_t)b * 64 + n) * 4);

        float x1f = fminf(bx.x, bx.z) * 100.f;
        float x2f = fmaxf(bx.x, bx.z) * 100.f;
        float y1f = fminf(bx.y, bx.w) * 100.f;
        float y2f = fmaxf(bx.y, bx.w) * 100.f;
        x1f = fminf(fmaxf(floorf(fminf(fmaxf(x1f, 0.f), 100.f)), 0.f), 100.f);
        x2f = fminf(fmaxf(ceilf (fminf(fmaxf(x2f, 0.f), 100.f)), 0.f), 100.f);
        y1f = fminf(fmaxf(floorf(fminf(fmaxf(y1f, 0.f), 100.f)), 0.f), 100.f);
        y2f = fminf(fmaxf(ceilf (fminf(fmaxf(y2f, 0.f), 100.f)), 0.f), 100.f);
        const int ix1 = (int)x1f, ix2 = (int)x2f;
        const int iy1 = (int)y1f, iy2 = (int)y2f;
        const int cnt = (ix2 - ix1) * (iy2 - iy1);

        float v = 0.f;
        if (cnt > 0) {
            const int colR = ix2 - 1;
            const int colL = ix1 - 1;
            for (int h = iy1 + j; h < iy2; h += 4) {
                float s = Sl[h * 100 + colR];
                if (colL >= 0) s -= Sl[h * 100 + colL];
                v += s;
            }
        }
        v += __shfl_xor(v, 1);
        v += __shfl_xor(v, 2);
        if (j == 0)
            pooled[((size_t)b * 64 + n) * Cq + c] = (cnt > 0) ? v / (float)cnt : 0.f;
    }
}

// ---------------------------------------------------------------------------
// Kernel 3: MLP (256->128 SiLU ->64) + L2 normalize. One block per (b,n).
// ---------------------------------------------------------------------------
__global__ __launch_bounds__(128) void mlp_kernel(const float* __restrict__ pooled,
                                                  const float* __restrict__ w1,
                                                  const float* __restrict__ b1,
                                                  const float* __restrict__ w2,
                                                  const float* __restrict__ b2,
                                                  float* __restrict__ emb,
                                                  float* __restrict__ raw) {
    __shared__ float ps[256];
    __shared__ float hs[128];
    const int bn = blockIdx.x;
    const int t  = threadIdx.x;

    ps[t]       = pooled[(size_t)bn * 256 + t];
    ps[t + 128] = pooled[(size_t)bn * 256 + t + 128];
    __syncthreads();

    float a = b1[t];
    #pragma unroll 8
    for (int c = 0; c < 256; ++c) a += ps[c] * w1[c * 128 + t];
    hs[t] = a / (1.f + __expf(-a));
    __syncthreads();

    if (t < 64) {
        float r = b2[t];
        #pragma unroll 8
        for (int h = 0; h < 128; ++h) r += hs[h] * w2[h * 64 + t];
        raw[(size_t)bn * 64 + t] = r;
        float s = r * r;
        #pragma unroll
        for (int m = 1; m < 64; m <<= 1) s += __shfl_xor(s, m);
        float nrm = fmaxf(sqrtf(s), 1e-6f);
        emb[(size_t)bn * 64 + t] = r / nrm;
    }
}

// ---------------------------------------------------------------------------
extern "C" void kernel_launch(void* const* d_in, const int* in_sizes, int n_in,
                              void* d_out, int out_size, void* d_ws, size_t ws_size,
                              hipStream_t stream) {
    const float* feat  = (const float*)d_in[0];
    const float* boxes = (const float*)d_in[1];
    const float* convw = (const float*)d_in[2];
    const float* gnw   = (const float*)d_in[3];
    const float* gnb   = (const float*)d_in[4];
    const float* w1    = (const float*)d_in[5];
    const float* b1    = (const float*)d_in[6];
    const float* w2    = (const float*)d_in[7];
    const float* b2    = (const float*)d_in[8];

    float* out    = (float*)d_out;
    float* emb    = out;             // [8,64,64]   = 32768
    float* raw    = out + 32768;     // [8,64,64]   = 32768
    float* pooled = out + 65536;     // [8,64,256]  = 131072

    unsigned short* y = (unsigned short*)d_ws;                     // 8*256*10000 bf16
    float* stats = (float*)((char*)d_ws + (size_t)8 * 256 * 10000 * 2);

    hipMemsetAsync(stats, 0, 16 * sizeof(float), stream);

    dim3 g1((HWq + 127) / 128, 2, 8);   // 79 x 2 x 8
    conv_mfma<<<g1, 256, 0, stream>>>(feat, convw, y, stats);

    integral_pool<<<2048, 256, 0, stream>>>(y, boxes, stats, gnw, gnb, pooled);

    mlp_kernel<<<512, 128, 0, stream>>>(pooled, w1, b1, w2, b2, emb, raw);
}

// Round 12
// 216.846 us; speedup vs baseline: 16.7703x; 1.0619x over previous
//
#include <hip/hip_runtime.h>
#include <hip/hip_bf16.h>
#include <math.h>

#define HWq 10000
#define Cq 256   // in channels (K)
#define Oq 256   // out channels (M)

typedef __attribute__((ext_vector_type(8))) short short8v;           // 8 bf16
typedef __attribute__((ext_vector_type(4))) float f32x4;

__device__ __forceinline__ short f2bf(float f) {
    __hip_bfloat16 h = __float2bfloat16(f);      // RNE; pairs fuse to v_cvt_pk_bf16_f32
    return *reinterpret_cast<short*>(&h);
}
__device__ __forceinline__ float bf2f(unsigned short u) {
    return __uint_as_float((unsigned)u << 16);
}

// XOR swizzle of 16B units within a 64B k-row
__device__ __forceinline__ int swz(int row, int g) {
    return g ^ (row & 3) ^ ((row >> 2) & 1);
}

// ---------------------------------------------------------------------------
// Kernel 1: 1x1 conv as bf16 MFMA GEMM, y stored as bf16.
// Block tile 128o x 128p, BK=32, 4 waves (2x2), single LDS buffer (16.9 KB),
// reg-prefetch of next K-tile issued between barrier and MFMA.
// (Round-9 structure: 61 us measured; double-buffer variant regressed to 80.)
// Accumulates per-batch sum/sumsq (f32) into stats[0..7] / stats[8..15].
// ---------------------------------------------------------------------------
__global__ __launch_bounds__(256) void conv_mfma(const float* __restrict__ feat,
                                                 const float* __restrict__ convw,
                                                 unsigned short* __restrict__ y,
                                                 float* __restrict__ stats) {
    __shared__ __align__(16) short Albuf[128 * 32];   // [o][k] bf16, swizzled
    __shared__ __align__(16) short Blbuf[128 * 32];   // [p][k] bf16, swizzled
    __shared__ float redbuf[8];

    const int b  = blockIdx.z;
    const int o0 = blockIdx.y * 128;
    const int p0 = blockIdx.x * 128;
    const int t  = threadIdx.x;
    const int w  = t >> 6;
    const int l  = t & 63;
    const int wo = (w >> 1) * 64;
    const int wp = (w & 1) * 64;

    const float* fb = feat + (size_t)b * Cq * HWq;

    f32x4 acc[4][4];
    #pragma unroll
    for (int i = 0; i < 4; ++i)
        #pragma unroll
        for (int j = 0; j < 4; ++j)
            acc[i][j] = (f32x4){0.f, 0.f, 0.f, 0.f};

    const int oA0 = t >> 2;
    const int oA1 = oA0 + 64;
    const int kuA = t & 3;
    const float* aptr0 = convw + (size_t)(o0 + oA0) * Cq + kuA * 8;
    const float* aptr1 = convw + (size_t)(o0 + oA1) * Cq + kuA * 8;

    int pgB[2];
    #pragma unroll
    for (int pass = 0; pass < 2; ++pass) {
        int pg = p0 + pass * 64 + l;
        pgB[pass] = (pg > HWq - 1) ? (HWq - 1) : pg;
    }

    const int fr_g = l >> 4;
    const int fr_r = l & 15;

    float4 ra0, ra1, ra2, ra3;
    float  rb[2][8];

    auto LOADG = [&](int k0) {
        ra0 = *(const float4*)(aptr0 + k0);
        ra1 = *(const float4*)(aptr0 + k0 + 4);
        ra2 = *(const float4*)(aptr1 + k0);
        ra3 = *(const float4*)(aptr1 + k0 + 4);
        #pragma unroll
        for (int pass = 0; pass < 2; ++pass) {
            const float* fk = fb + (size_t)(k0 + w * 8) * HWq + pgB[pass];
            #pragma unroll
            for (int jj = 0; jj < 8; ++jj)
                rb[pass][jj] = fk[(size_t)jj * HWq];
        }
    };

    LOADG(0);

    for (int k0 = 0; k0 < Cq; k0 += 32) {
        if (k0) __syncthreads();               // LDS reads of prev step done

        // ---- LDS write from regs (f32 -> bf16)
        {
            short8v s;
            s[0]=f2bf(ra0.x); s[1]=f2bf(ra0.y); s[2]=f2bf(ra0.z); s[3]=f2bf(ra0.w);
            s[4]=f2bf(ra1.x); s[5]=f2bf(ra1.y); s[6]=f2bf(ra1.z); s[7]=f2bf(ra1.w);
            *(short8v*)((char*)Albuf + oA0 * 64 + swz(oA0, kuA) * 16) = s;
            short8v s2;
            s2[0]=f2bf(ra2.x); s2[1]=f2bf(ra2.y); s2[2]=f2bf(ra2.z); s2[3]=f2bf(ra2.w);
            s2[4]=f2bf(ra3.x); s2[5]=f2bf(ra3.y); s2[6]=f2bf(ra3.z); s2[7]=f2bf(ra3.w);
            *(short8v*)((char*)Albuf + oA1 * 64 + swz(oA1, kuA) * 16) = s2;
            #pragma unroll
            for (int pass = 0; pass < 2; ++pass) {
                short8v sb;
                #pragma unroll
                for (int jj = 0; jj < 8; ++jj) sb[jj] = f2bf(rb[pass][jj]);
                int p = pass * 64 + l;
                *(short8v*)((char*)Blbuf + p * 64 + swz(p, w) * 16) = sb;
            }
        }
        __syncthreads();

        if (k0 < Cq - 32) LOADG(k0 + 32);      // prefetch next chunk (hides under MFMA)

        short8v af[4], bfv[4];
        #pragma unroll
        for (int i = 0; i < 4; ++i) {
            int row = wo + i * 16 + fr_r;
            af[i] = *(const short8v*)((const char*)Albuf + row * 64 + swz(row, fr_g) * 16);
        }
        #pragma unroll
        for (int j = 0; j < 4; ++j) {
            int row = wp + j * 16 + fr_r;
            bfv[j] = *(const short8v*)((const char*)Blbuf + row * 64 + swz(row, fr_g) * 16);
        }
        #pragma unroll
        for (int i = 0; i < 4; ++i)
            #pragma unroll
            for (int j = 0; j < 4; ++j)
                acc[i][j] = __builtin_amdgcn_mfma_f32_16x16x32_bf16(af[i], bfv[j], acc[i][j], 0, 0, 0);
    }

    // ---- epilogue: bf16 y store + f32 stats
    float lsum = 0.f, lsq = 0.f;
    #pragma unroll
    for (int i = 0; i < 4; ++i) {
        const int obase = o0 + wo + i * 16 + (l >> 4) * 4;
        #pragma unroll
        for (int j = 0; j < 4; ++j) {
            const int p = p0 + wp + j * 16 + (l & 15);
            if (p < HWq) {
                #pragma unroll
                for (int r = 0; r < 4; ++r) {
                    float v = acc[i][j][r];
                    y[((size_t)(b * Oq + obase + r)) * HWq + p] = (unsigned short)f2bf(v);
                    lsum += v;
                    lsq  += v * v;
                }
            }
        }
    }
    #pragma unroll
    for (int m = 1; m < 64; m <<= 1) {
        lsum += __shfl_xor(lsum, m);
        lsq  += __shfl_xor(lsq, m);
    }
    if (l == 0) { redbuf[w] = lsum; redbuf[4 + w] = lsq; }
    __syncthreads();
    if (t == 0) {
        atomicAdd(&stats[b],     redbuf[0] + redbuf[1] + redbuf[2] + redbuf[3]);
        atomicAdd(&stats[8 + b], redbuf[4] + redbuf[5] + redbuf[6] + redbuf[7]);
    }
}

// ---------------------------------------------------------------------------
// Kernel 2: per-(b,c) plane. Each wave loads its own rows from global,
// normalizes+SiLUs in-register, does a 50-lane pair-scan (row prefix along x),
// writes prefix to LDS. Pooling = per-box row-range sums (no column scan).
// ---------------------------------------------------------------------------
__global__ __launch_bounds__(256) void integral_pool(const unsigned short* __restrict__ y,
                                                     const float* __restrict__ boxes,
                                                     const float* __restrict__ stats,
                                                     const float* __restrict__ gnw,
                                                     const float* __restrict__ gnb,
                                                     float* __restrict__ pooled) {
    __shared__ float Sl[10000];          // row-prefix values

    const int plane = blockIdx.x;        // b*256 + c
    const int b = plane >> 8;
    const int c = plane & 255;
    const int wave = threadIdx.x >> 6;
    const int lane = threadIdx.x & 63;

    const float invM = 1.f / 2560000.f;
    const float mu   = stats[b] * invM;
    const float msq  = stats[8 + b] * invM;
    const float rs   = rsqrtf(msq - mu * mu + 1e-5f);
    const float scale = gnw[c] * rs;
    const float shift = gnb[c] - mu * scale;

    const unsigned short* yp = y + (size_t)plane * HWq;

    // row prefix: wave owns rows wave+4i, i=0..24; 2-row ILP unroll.
    for (int i = 0; i < 25; i += 2) {
        const int r0 = wave + 4 * i;
        const int r1 = r0 + 4;
        const bool has1 = (i + 1) < 25;
        float a0 = 0.f, b0 = 0.f, a1 = 0.f, b1 = 0.f;
        if (lane < 50) {
            ushort2 u0 = *(const ushort2*)(yp + r0 * 100 + 2 * lane);
            float v0 = bf2f(u0.x) * scale + shift;
            float v1 = bf2f(u0.y) * scale + shift;
            a0 = v0 / (1.f + __expf(-v0));
            b0 = v1 / (1.f + __expf(-v1));
            if (has1) {
                ushort2 u1 = *(const ushort2*)(yp + r1 * 100 + 2 * lane);
                float w0 = bf2f(u1.x) * scale + shift;
                float w1 = bf2f(u1.y) * scale + shift;
                a1 = w0 / (1.f + __expf(-w0));
                b1 = w1 / (1.f + __expf(-w1));
            }
        }
        float p0 = a0 + b0;
        float p1 = a1 + b1;
        #pragma unroll
        for (int m = 1; m < 64; m <<= 1) {
            float t0 = __shfl_up(p0, m);
            float t1 = __shfl_up(p1, m);
            if (lane >= m) { p0 += t0; p1 += t1; }
        }
        if (lane < 50) {
            float2 o0 = {p0 - b0, p0};            // inclusive prefix at x=2l, 2l+1
            *(float2*)(&Sl[r0 * 100 + 2 * lane]) = o0;
            if (has1) {
                float2 o1 = {p1 - b1, p1};
                *(float2*)(&Sl[r1 * 100 + 2 * lane]) = o1;
            }
        }
    }
    __syncthreads();

    // pooling: 4 lanes per box; lane j sums rows iy1+j, step 4
    {
        const int grp = lane >> 2;           // 0..15
        const int j   = lane & 3;
        const int n   = wave * 16 + grp;     // 0..63
        const float4 bx = *(const float4*)(boxes + ((size_t)b * 64 + n) * 4);

        float x1f = fminf(bx.x, bx.z) * 100.f;
        float x2f = fmaxf(bx.x, bx.z) * 100.f;
        float y1f = fminf(bx.y, bx.w) * 100.f;
        float y2f = fmaxf(bx.y, bx.w) * 100.f;
        x1f = fminf(fmaxf(floorf(fminf(fmaxf(x1f, 0.f), 100.f)), 0.f), 100.f);
        x2f = fminf(fmaxf(ceilf (fminf(fmaxf(x2f, 0.f), 100.f)), 0.f), 100.f);
        y1f = fminf(fmaxf(floorf(fminf(fmaxf(y1f, 0.f), 100.f)), 0.f), 100.f);
        y2f = fminf(fmaxf(ceilf (fminf(fmaxf(y2f, 0.f), 100.f)), 0.f), 100.f);
        const int ix1 = (int)x1f, ix2 = (int)x2f;
        const int iy1 = (int)y1f, iy2 = (int)y2f;
        const int cnt = (ix2 - ix1) * (iy2 - iy1);

        float v = 0.f;
        if (cnt > 0) {
            const int colR = ix2 - 1;
            const int colL = ix1 - 1;
            for (int h = iy1 + j; h < iy2; h += 4) {
                float s = Sl[h * 100 + colR];
                if (colL >= 0) s -= Sl[h * 100 + colL];
                v += s;
            }
        }
        v += __shfl_xor(v, 1);
        v += __shfl_xor(v, 2);
        if (j == 0)
            pooled[((size_t)b * 64 + n) * Cq + c] = (cnt > 0) ? v / (float)cnt : 0.f;
    }
}

// ---------------------------------------------------------------------------
// Kernel 3: MLP (256->128 SiLU ->64) + L2 normalize. One block per (b,n).
// 4-way ILP accumulators break the dependent-FMA chain.
// ---------------------------------------------------------------------------
__global__ __launch_bounds__(128) void mlp_kernel(const float* __restrict__ pooled,
                                                  const float* __restrict__ w1,
                                                  const float* __restrict__ b1,
                                                  const float* __restrict__ w2,
                                                  const float* __restrict__ b2,
                                                  float* __restrict__ emb,
                                                  float* __restrict__ raw) {
    __shared__ float ps[256];
    __shared__ float hs[128];
    const int bn = blockIdx.x;
    const int t  = threadIdx.x;

    ps[t]       = pooled[(size_t)bn * 256 + t];
    ps[t + 128] = pooled[(size_t)bn * 256 + t + 128];
    __syncthreads();

    float a0 = 0.f, a1 = 0.f, a2 = 0.f, a3 = 0.f;
    #pragma unroll 4
    for (int c = 0; c < 256; c += 4) {
        a0 += ps[c]     * w1[c * 128 + t];
        a1 += ps[c + 1] * w1[(c + 1) * 128 + t];
        a2 += ps[c + 2] * w1[(c + 2) * 128 + t];
        a3 += ps[c + 3] * w1[(c + 3) * 128 + t];
    }
    float a = b1[t] + ((a0 + a1) + (a2 + a3));
    hs[t] = a / (1.f + __expf(-a));
    __syncthreads();

    if (t < 64) {
        float r0 = 0.f, r1 = 0.f, r2 = 0.f, r3 = 0.f;
        #pragma unroll 4
        for (int h = 0; h < 128; h += 4) {
            r0 += hs[h]     * w2[h * 64 + t];
            r1 += hs[h + 1] * w2[(h + 1) * 64 + t];
            r2 += hs[h + 2] * w2[(h + 2) * 64 + t];
            r3 += hs[h + 3] * w2[(h + 3) * 64 + t];
        }
        float r = b2[t] + ((r0 + r1) + (r2 + r3));
        raw[(size_t)bn * 64 + t] = r;
        float s = r * r;
        #pragma unroll
        for (int m = 1; m < 64; m <<= 1) s += __shfl_xor(s, m);
        float nrm = fmaxf(sqrtf(s), 1e-6f);
        emb[(size_t)bn * 64 + t] = r / nrm;
    }
}

// ---------------------------------------------------------------------------
extern "C" void kernel_launch(void* const* d_in, const int* in_sizes, int n_in,
                              void* d_out, int out_size, void* d_ws, size_t ws_size,
                              hipStream_t stream) {
    const float* feat  = (const float*)d_in[0];
    const float* boxes = (const float*)d_in[1];
    const float* convw = (const float*)d_in[2];
    const float* gnw   = (const float*)d_in[3];
    const float* gnb   = (const float*)d_in[4];
    const float* w1    = (const float*)d_in[5];
    const float* b1    = (const float*)d_in[6];
    const float* w2    = (const float*)d_in[7];
    const float* b2    = (const float*)d_in[8];

    float* out    = (float*)d_out;
    float* emb    = out;             // [8,64,64]   = 32768
    float* raw    = out + 32768;     // [8,64,64]   = 32768
    float* pooled = out + 65536;     // [8,64,256]  = 131072

    unsigned short* y = (unsigned short*)d_ws;                     // 8*256*10000 bf16
    float* stats = (float*)((char*)d_ws + (size_t)8 * 256 * 10000 * 2);

    hipMemsetAsync(stats, 0, 16 * sizeof(float), stream);

    dim3 g1((HWq + 127) / 128, 2, 8);   // 79 x 2 x 8
    conv_mfma<<<g1, 256, 0, stream>>>(feat, convw, y, stats);

    integral_pool<<<2048, 256, 0, stream>>>(y, boxes, stats, gnw, gnb, pooled);

    mlp_kernel<<<512, 128, 0, stream>>>(pooled, w1, b1, w2, b2, emb, raw);
}

// Round 13
// 208.418 us; speedup vs baseline: 17.4485x; 1.0404x over previous
//
#include <hip/hip_runtime.h>
#include <hip/hip_bf16.h>
#include <math.h>

#define HWq 10000
#define Cq 256   // in channels (K)
#define Oq 256   // out channels (M)

typedef __attribute__((ext_vector_type(8))) short short8v;           // 8 bf16
typedef __attribute__((ext_vector_type(4))) float f32x4;

__device__ __forceinline__ short f2bf(float f) {
    __hip_bfloat16 h = __float2bfloat16(f);      // RNE; pairs fuse to v_cvt_pk_bf16_f32
    return *reinterpret_cast<short*>(&h);
}
__device__ __forceinline__ float bf2f(unsigned short u) {
    return __uint_as_float((unsigned)u << 16);
}

// XOR swizzle of 16B units within a 64B k-row
__device__ __forceinline__ int swz(int row, int g) {
    return g ^ (row & 3) ^ ((row >> 2) & 1);
}

// ---------------------------------------------------------------------------
// Kernel 1: 1x1 conv as bf16 MFMA GEMM, y stored as bf16. (R12 structure,
// measured 61 us; dbuf variant regressed to 80 — do not re-add.)
// ---------------------------------------------------------------------------
__global__ __launch_bounds__(256) void conv_mfma(const float* __restrict__ feat,
                                                 const float* __restrict__ convw,
                                                 unsigned short* __restrict__ y,
                                                 float* __restrict__ stats) {
    __shared__ __align__(16) short Albuf[128 * 32];   // [o][k] bf16, swizzled
    __shared__ __align__(16) short Blbuf[128 * 32];   // [p][k] bf16, swizzled
    __shared__ float redbuf[8];

    const int b  = blockIdx.z;
    const int o0 = blockIdx.y * 128;
    const int p0 = blockIdx.x * 128;
    const int t  = threadIdx.x;
    const int w  = t >> 6;
    const int l  = t & 63;
    const int wo = (w >> 1) * 64;
    const int wp = (w & 1) * 64;

    const float* fb = feat + (size_t)b * Cq * HWq;

    f32x4 acc[4][4];
    #pragma unroll
    for (int i = 0; i < 4; ++i)
        #pragma unroll
        for (int j = 0; j < 4; ++j)
            acc[i][j] = (f32x4){0.f, 0.f, 0.f, 0.f};

    const int oA0 = t >> 2;
    const int oA1 = oA0 + 64;
    const int kuA = t & 3;
    const float* aptr0 = convw + (size_t)(o0 + oA0) * Cq + kuA * 8;
    const float* aptr1 = convw + (size_t)(o0 + oA1) * Cq + kuA * 8;

    int pgB[2];
    #pragma unroll
    for (int pass = 0; pass < 2; ++pass) {
        int pg = p0 + pass * 64 + l;
        pgB[pass] = (pg > HWq - 1) ? (HWq - 1) : pg;
    }

    const int fr_g = l >> 4;
    const int fr_r = l & 15;

    float4 ra0, ra1, ra2, ra3;
    float  rb[2][8];

    auto LOADG = [&](int k0) {
        ra0 = *(const float4*)(aptr0 + k0);
        ra1 = *(const float4*)(aptr0 + k0 + 4);
        ra2 = *(const float4*)(aptr1 + k0);
        ra3 = *(const float4*)(aptr1 + k0 + 4);
        #pragma unroll
        for (int pass = 0; pass < 2; ++pass) {
            const float* fk = fb + (size_t)(k0 + w * 8) * HWq + pgB[pass];
            #pragma unroll
            for (int jj = 0; jj < 8; ++jj)
                rb[pass][jj] = fk[(size_t)jj * HWq];
        }
    };

    LOADG(0);

    for (int k0 = 0; k0 < Cq; k0 += 32) {
        if (k0) __syncthreads();               // LDS reads of prev step done

        // ---- LDS write from regs (f32 -> bf16)
        {
            short8v s;
            s[0]=f2bf(ra0.x); s[1]=f2bf(ra0.y); s[2]=f2bf(ra0.z); s[3]=f2bf(ra0.w);
            s[4]=f2bf(ra1.x); s[5]=f2bf(ra1.y); s[6]=f2bf(ra1.z); s[7]=f2bf(ra1.w);
            *(short8v*)((char*)Albuf + oA0 * 64 + swz(oA0, kuA) * 16) = s;
            short8v s2;
            s2[0]=f2bf(ra2.x); s2[1]=f2bf(ra2.y); s2[2]=f2bf(ra2.z); s2[3]=f2bf(ra2.w);
            s2[4]=f2bf(ra3.x); s2[5]=f2bf(ra3.y); s2[6]=f2bf(ra3.z); s2[7]=f2bf(ra3.w);
            *(short8v*)((char*)Albuf + oA1 * 64 + swz(oA1, kuA) * 16) = s2;
            #pragma unroll
            for (int pass = 0; pass < 2; ++pass) {
                short8v sb;
                #pragma unroll
                for (int jj = 0; jj < 8; ++jj) sb[jj] = f2bf(rb[pass][jj]);
                int p = pass * 64 + l;
                *(short8v*)((char*)Blbuf + p * 64 + swz(p, w) * 16) = sb;
            }
        }
        __syncthreads();

        if (k0 < Cq - 32) LOADG(k0 + 32);      // prefetch next chunk (hides under MFMA)

        short8v af[4], bfv[4];
        #pragma unroll
        for (int i = 0; i < 4; ++i) {
            int row = wo + i * 16 + fr_r;
            af[i] = *(const short8v*)((const char*)Albuf + row * 64 + swz(row, fr_g) * 16);
        }
        #pragma unroll
        for (int j = 0; j < 4; ++j) {
            int row = wp + j * 16 + fr_r;
            bfv[j] = *(const short8v*)((const char*)Blbuf + row * 64 + swz(row, fr_g) * 16);
        }
        #pragma unroll
        for (int i = 0; i < 4; ++i)
            #pragma unroll
            for (int j = 0; j < 4; ++j)
                acc[i][j] = __builtin_amdgcn_mfma_f32_16x16x32_bf16(af[i], bfv[j], acc[i][j], 0, 0, 0);
    }

    // ---- epilogue: bf16 y store + f32 stats
    float lsum = 0.f, lsq = 0.f;
    #pragma unroll
    for (int i = 0; i < 4; ++i) {
        const int obase = o0 + wo + i * 16 + (l >> 4) * 4;
        #pragma unroll
        for (int j = 0; j < 4; ++j) {
            const int p = p0 + wp + j * 16 + (l & 15);
            if (p < HWq) {
                #pragma unroll
                for (int r = 0; r < 4; ++r) {
                    float v = acc[i][j][r];
                    y[((size_t)(b * Oq + obase + r)) * HWq + p] = (unsigned short)f2bf(v);
                    lsum += v;
                    lsq  += v * v;
                }
            }
        }
    }
    #pragma unroll
    for (int m = 1; m < 64; m <<= 1) {
        lsum += __shfl_xor(lsum, m);
        lsq  += __shfl_xor(lsq, m);
    }
    if (l == 0) { redbuf[w] = lsum; redbuf[4 + w] = lsq; }
    __syncthreads();
    if (t == 0) {
        atomicAdd(&stats[b],     redbuf[0] + redbuf[1] + redbuf[2] + redbuf[3]);
        atomicAdd(&stats[8 + b], redbuf[4] + redbuf[5] + redbuf[6] + redbuf[7]);
    }
}

// ---------------------------------------------------------------------------
// Kernel 2: per-(b,c) plane, 8 waves (512 threads). Each wave owns rows
// wave+8i (halves the serial scan-iteration count vs 4-wave version).
// Row prefix along x in LDS; pooling = per-box row-range sums, 8 lanes/box.
// ---------------------------------------------------------------------------
__global__ __launch_bounds__(512) void integral_pool(const unsigned short* __restrict__ y,
                                                     const float* __restrict__ boxes,
                                                     const float* __restrict__ stats,
                                                     const float* __restrict__ gnw,
                                                     const float* __restrict__ gnb,
                                                     float* __restrict__ pooled) {
    __shared__ float Sl[10000];          // row-prefix values

    const int plane = blockIdx.x;        // b*256 + c
    const int b = plane >> 8;
    const int c = plane & 255;
    const int wave = threadIdx.x >> 6;   // 0..7
    const int lane = threadIdx.x & 63;

    const float invM = 1.f / 2560000.f;
    const float mu   = stats[b] * invM;
    const float msq  = stats[8 + b] * invM;
    const float rs   = rsqrtf(msq - mu * mu + 1e-5f);
    const float scale = gnw[c] * rs;
    const float shift = gnb[c] - mu * scale;

    const unsigned short* yp = y + (size_t)plane * HWq;

    // row prefix: wave owns rows wave+8i; 2-row ILP unroll (7 iterations).
    for (int i = 0; i < 13; i += 2) {
        const int r0 = wave + 8 * i;
        const int r1 = r0 + 8;
        const bool has0 = r0 < 100;
        const bool has1 = r1 < 100;
        float a0 = 0.f, b0 = 0.f, a1 = 0.f, b1 = 0.f;
        if (lane < 50) {
            if (has0) {
                ushort2 u0 = *(const ushort2*)(yp + r0 * 100 + 2 * lane);
                float v0 = bf2f(u0.x) * scale + shift;
                float v1 = bf2f(u0.y) * scale + shift;
                a0 = v0 / (1.f + __expf(-v0));
                b0 = v1 / (1.f + __expf(-v1));
            }
            if (has1) {
                ushort2 u1 = *(const ushort2*)(yp + r1 * 100 + 2 * lane);
                float w0 = bf2f(u1.x) * scale + shift;
                float w1 = bf2f(u1.y) * scale + shift;
                a1 = w0 / (1.f + __expf(-w0));
                b1 = w1 / (1.f + __expf(-w1));
            }
        }
        float p0 = a0 + b0;
        float p1 = a1 + b1;
        #pragma unroll
        for (int m = 1; m < 64; m <<= 1) {
            float t0 = __shfl_up(p0, m);
            float t1 = __shfl_up(p1, m);
            if (lane >= m) { p0 += t0; p1 += t1; }
        }
        if (lane < 50) {
            if (has0) {
                float2 o0 = {p0 - b0, p0};            // inclusive prefix at x=2l, 2l+1
                *(float2*)(&Sl[r0 * 100 + 2 * lane]) = o0;
            }
            if (has1) {
                float2 o1 = {p1 - b1, p1};
                *(float2*)(&Sl[r1 * 100 + 2 * lane]) = o1;
            }
        }
    }
    __syncthreads();

    // pooling: 8 lanes per box; lane j sums rows iy1+j, step 8
    {
        const int grp = lane >> 3;           // 0..7
        const int j   = lane & 7;
        const int n   = wave * 8 + grp;      // 0..63
        const float4 bx = *(const float4*)(boxes + ((size_t)b * 64 + n) * 4);

        float x1f = fminf(bx.x, bx.z) * 100.f;
        float x2f = fmaxf(bx.x, bx.z) * 100.f;
        float y1f = fminf(bx.y, bx.w) * 100.f;
        float y2f = fmaxf(bx.y, bx.w) * 100.f;
        x1f = fminf(fmaxf(floorf(fminf(fmaxf(x1f, 0.f), 100.f)), 0.f), 100.f);
        x2f = fminf(fmaxf(ceilf (fminf(fmaxf(x2f, 0.f), 100.f)), 0.f), 100.f);
        y1f = fminf(fmaxf(floorf(fminf(fmaxf(y1f, 0.f), 100.f)), 0.f), 100.f);
        y2f = fminf(fmaxf(ceilf (fminf(fmaxf(y2f, 0.f), 100.f)), 0.f), 100.f);
        const int ix1 = (int)x1f, ix2 = (int)x2f;
        const int iy1 = (int)y1f, iy2 = (int)y2f;
        const int cnt = (ix2 - ix1) * (iy2 - iy1);

        float v = 0.f;
        if (cnt > 0) {
            const int colR = ix2 - 1;
            const int colL = ix1 - 1;
            for (int h = iy1 + j; h < iy2; h += 8) {
                float s = Sl[h * 100 + colR];
                if (colL >= 0) s -= Sl[h * 100 + colL];
                v += s;
            }
        }
        v += __shfl_xor(v, 1);
        v += __shfl_xor(v, 2);
        v += __shfl_xor(v, 4);
        if (j == 0)
            pooled[((size_t)b * 64 + n) * Cq + c] = (cnt > 0) ? v / (float)cnt : 0.f;
    }
}

// ---------------------------------------------------------------------------
// Kernel 3: MLP (256->128 SiLU ->64) + L2 normalize. One block per (b,n).
// 4-way ILP accumulators break the dependent-FMA chain.
// ---------------------------------------------------------------------------
__global__ __launch_bounds__(128) void mlp_kernel(const float* __restrict__ pooled,
                                                  const float* __restrict__ w1,
                                                  const float* __restrict__ b1,
                                                  const float* __restrict__ w2,
                                                  const float* __restrict__ b2,
                                                  float* __restrict__ emb,
                                                  float* __restrict__ raw) {
    __shared__ float ps[256];
    __shared__ float hs[128];
    const int bn = blockIdx.x;
    const int t  = threadIdx.x;

    ps[t]       = pooled[(size_t)bn * 256 + t];
    ps[t + 128] = pooled[(size_t)bn * 256 + t + 128];
    __syncthreads();

    float a0 = 0.f, a1 = 0.f, a2 = 0.f, a3 = 0.f;
    #pragma unroll 4
    for (int c = 0; c < 256; c += 4) {
        a0 += ps[c]     * w1[c * 128 + t];
        a1 += ps[c + 1] * w1[(c + 1) * 128 + t];
        a2 += ps[c + 2] * w1[(c + 2) * 128 + t];
        a3 += ps[c + 3] * w1[(c + 3) * 128 + t];
    }
    float a = b1[t] + ((a0 + a1) + (a2 + a3));
    hs[t] = a / (1.f + __expf(-a));
    __syncthreads();

    if (t < 64) {
        float r0 = 0.f, r1 = 0.f, r2 = 0.f, r3 = 0.f;
        #pragma unroll 4
        for (int h = 0; h < 128; h += 4) {
            r0 += hs[h]     * w2[h * 64 + t];
            r1 += hs[h + 1] * w2[(h + 1) * 64 + t];
            r2 += hs[h + 2] * w2[(h + 2) * 64 + t];
            r3 += hs[h + 3] * w2[(h + 3) * 64 + t];
        }
        float r = b2[t] + ((r0 + r1) + (r2 + r3));
        raw[(size_t)bn * 64 + t] = r;
        float s = r * r;
        #pragma unroll
        for (int m = 1; m < 64; m <<= 1) s += __shfl_xor(s, m);
        float nrm = fmaxf(sqrtf(s), 1e-6f);
        emb[(size_t)bn * 64 + t] = r / nrm;
    }
}

// ---------------------------------------------------------------------------
extern "C" void kernel_launch(void* const* d_in, const int* in_sizes, int n_in,
                              void* d_out, int out_size, void* d_ws, size_t ws_size,
                              hipStream_t stream) {
    const float* feat  = (const float*)d_in[0];
    const float* boxes = (const float*)d_in[1];
    const float* convw = (const float*)d_in[2];
    const float* gnw   = (const float*)d_in[3];
    const float* gnb   = (const float*)d_in[4];
    const float* w1    = (const float*)d_in[5];
    const float* b1    = (const float*)d_in[6];
    const float* w2    = (const float*)d_in[7];
    const float* b2    = (const float*)d_in[8];

    float* out    = (float*)d_out;
    float* emb    = out;             // [8,64,64]   = 32768
    float* raw    = out + 32768;     // [8,64,64]   = 32768
    float* pooled = out + 65536;     // [8,64,256]  = 131072

    unsigned short* y = (unsigned short*)d_ws;                     // 8*256*10000 bf16
    float* stats = (float*)((char*)d_ws + (size_t)8 * 256 * 10000 * 2);

    hipMemsetAsync(stats, 0, 16 * sizeof(float), stream);

    dim3 g1((HWq + 127) / 128, 2, 8);   // 79 x 2 x 8
    conv_mfma<<<g1, 256, 0, stream>>>(feat, convw, y, stats);

    integral_pool<<<2048, 512, 0, stream>>>(y, boxes, stats, gnw, gnb, pooled);

    mlp_kernel<<<512, 128, 0, stream>>>(pooled, w1, b1, w2, b2, emb, raw);
}